// Round 1
// baseline (65.301 us; speedup 1.0000x reference)
//
#include <hip/hip_runtime.h>

// BCE-sum reduction over 2×128MiB fp32 inputs → scalar.
// Memory-bound: 268 MB read @ ~6.3 TB/s achievable → ~43 µs floor.

__device__ __forceinline__ float bce_term(float p, float t) {
    const float LOG_CLAMP = -100.0f;
    float lp   = fmaxf(__logf(p),        LOG_CLAMP);
    float l1mp = fmaxf(__logf(1.0f - p), LOG_CLAMP);
    return -(t * lp + (1.0f - t) * l1mp);
}

__global__ void __launch_bounds__(256) bce_sum_kernel(
        const float4* __restrict__ p4,
        const float4* __restrict__ t4,
        float* __restrict__ out,
        int n4) {
    int i = blockIdx.x * blockDim.x + threadIdx.x;
    const int stride = gridDim.x * blockDim.x;
    float acc = 0.0f;
    for (; i < n4; i += stride) {
        float4 p = p4[i];
        float4 t = t4[i];
        acc += bce_term(p.x, t.x);
        acc += bce_term(p.y, t.y);
        acc += bce_term(p.z, t.z);
        acc += bce_term(p.w, t.w);
    }
    // wave (64-lane) reduce
    #pragma unroll
    for (int off = 32; off > 0; off >>= 1)
        acc += __shfl_down(acc, off, 64);

    __shared__ float wave_sums[4];  // 256 threads = 4 waves
    int lane = threadIdx.x & 63;
    int wave = threadIdx.x >> 6;
    if (lane == 0) wave_sums[wave] = acc;
    __syncthreads();
    if (wave == 0) {
        float s = (lane < 4) ? wave_sums[lane] : 0.0f;
        #pragma unroll
        for (int off = 2; off > 0; off >>= 1)
            s += __shfl_down(s, off, 64);
        if (lane == 0) atomicAdd(out, s);
    }
}

extern "C" void kernel_launch(void* const* d_in, const int* in_sizes, int n_in,
                              void* d_out, int out_size, void* d_ws, size_t ws_size,
                              hipStream_t stream) {
    const float* predict = (const float*)d_in[0];
    const float* target  = (const float*)d_in[1];
    float* out = (float*)d_out;

    int n  = in_sizes[0];      // 33,554,432 (divisible by 4)
    int n4 = n / 4;

    // d_out is poisoned to 0xAA before timing and never re-poisoned; we
    // accumulate with atomics, so zero it each call (async memset is
    // graph-capture safe).
    hipMemsetAsync(d_out, 0, sizeof(float), stream);

    const int block = 256;
    const int grid  = 2048;    // 256 CU × 8 blocks; grid-stride covers the rest
    bce_sum_kernel<<<grid, block, 0, stream>>>(
        (const float4*)predict, (const float4*)target, out, n4);
}